// Round 1
// baseline (7347.691 us; speedup 1.0000x reference)
//
#include <hip/hip_runtime.h>
#include <cstdint>
#include <cstddef>

#define DEPTH 100
#define HID 1024
#define MROWS 4096

typedef _Float16 half8 __attribute__((ext_vector_type(8)));
typedef float floatx4 __attribute__((ext_vector_type(4)));

__device__ __forceinline__ void gload_lds16(const void* g, void* l) {
    __builtin_amdgcn_global_load_lds((const __attribute__((address_space(1))) void*)g,
                                     (__attribute__((address_space(3))) void*)l,
                                     16, 0, 0);
}

// C[M,N] = A[M,K](fp16) * B[N,K](fp32, converted to fp16 in-flight)^T  + epilogue
// MODE 0: fc1   -> hnew(fp32) + rnext(fp16, shifted by rshift)
// MODE 1: blk fc1 -> aout = fp16(relu(acc+bias))
// MODE 2: blk fc2 -> hnew = 0.97*shift(hold) + 0.03*(acc+bias); rnext = fp16(shift(hnew)) (or unshifted if rshift==0)
// MODE 3: fc2   -> outp(fp32)
template<int MODE>
__global__ __launch_bounds__(256, 2)
void gemm_k(const _Float16* __restrict__ A, const float* __restrict__ B,
            const float* __restrict__ bias, const float* __restrict__ hold,
            float* __restrict__ hnew, _Float16* __restrict__ rnext,
            _Float16* __restrict__ aout, float* __restrict__ outp,
            int N, int K, int rshift)
{
    __shared__ _Float16 As[128 * 64];   // [row 0..127][k 0..63], XOR-swizzled 16B chunks
    __shared__ _Float16 Bs[64 * 64];    // [col 0..63][k 0..63],  XOR-swizzled 16B chunks

    const int tid = threadIdx.x;
    const int l   = tid & 63;
    const int w   = tid >> 6;        // wave 0..3
    const int wm  = w >> 1;          // 0..1 along M
    const int wn  = w & 1;           // 0..1 along N
    const int bn  = blockIdx.x;
    const int bm  = blockIdx.y;

    floatx4 acc[4][2];
    const floatx4 zero = {0.f, 0.f, 0.f, 0.f};
    #pragma unroll
    for (int i = 0; i < 4; ++i)
        #pragma unroll
        for (int j = 0; j < 2; ++j) acc[i][j] = zero;

    // A-staging per-lane geometry (16 chunks of 1KB; chunk = 8 rows x 64 fp16)
    const int lr = l >> 3;           // row within chunk 0..7
    const int lj = l & 7;            // 16B-chunk column slot 0..7
    // B-staging geometry: thread -> (row, 32B quarter)
    const int br = tid >> 2;         // 0..63
    const int bq = tid & 3;          // 0..3
    // fragment-read swizzle (row&7 == l&7 for all frags since frag row base is mult of 16)
    const int sw = (l & 7) << 4;

    const int nkt = K >> 6;
    for (int kt = 0; kt < nkt; ++kt) {
        __syncthreads();
        // ---- stage A via global_load_lds (LDS linear, source pre-swizzled) ----
        #pragma unroll
        for (int q = 0; q < 4; ++q) {
            const int c   = w + 4 * q;           // chunk 0..15
            const int row = c * 8 + lr;          // 0..127
            const int jch = lj ^ (row & 7);      // swizzled source column chunk
            const _Float16* src = A + (size_t)(bm * 128 + row) * K + kt * 64 + jch * 8;
            gload_lds16((const void*)src, (void*)((char*)As + c * 1024));
        }
        // ---- stage B: fp32 -> fp16 in-register, swizzled ds_write ----
        {
            const float* bsrc = B + (size_t)(bn * 64 + br) * K + kt * 64 + bq * 16;
            const floatx4 f0 = ((const floatx4*)bsrc)[0];
            const floatx4 f1 = ((const floatx4*)bsrc)[1];
            const floatx4 f2 = ((const floatx4*)bsrc)[2];
            const floatx4 f3 = ((const floatx4*)bsrc)[3];
            half8 h0, h1;
            #pragma unroll
            for (int i = 0; i < 4; ++i) {
                h0[i]     = (_Float16)f0[i];
                h0[4 + i] = (_Float16)f1[i];
                h1[i]     = (_Float16)f2[i];
                h1[4 + i] = (_Float16)f3[i];
            }
            const int ob = br * 128 + bq * 32;
            const int s  = (br & 7) << 4;
            *(half8*)((char*)Bs + ((ob)      ^ s)) = h0;
            *(half8*)((char*)Bs + ((ob + 16) ^ s)) = h1;
        }
        __syncthreads();
        // ---- MFMA over the two K=32 halves ----
        #pragma unroll
        for (int kk = 0; kk < 2; ++kk) {
            half8 af[4], bf[2];
            #pragma unroll
            for (int fi = 0; fi < 4; ++fi) {
                const int off = ((wm * 64 + fi * 16 + (l & 15)) * 128 + kk * 64 + ((l >> 4) << 4)) ^ sw;
                af[fi] = *(const half8*)((const char*)As + off);
            }
            #pragma unroll
            for (int fj = 0; fj < 2; ++fj) {
                const int off = ((wn * 32 + fj * 16 + (l & 15)) * 128 + kk * 64 + ((l >> 4) << 4)) ^ sw;
                bf[fj] = *(const half8*)((const char*)Bs + off);
            }
            #pragma unroll
            for (int fi = 0; fi < 4; ++fi)
                #pragma unroll
                for (int fj = 0; fj < 2; ++fj)
                    acc[fi][fj] = __builtin_amdgcn_mfma_f32_16x16x32_f16(af[fi], bf[fj], acc[fi][fj], 0, 0, 0);
        }
    }

    // ---- epilogue ----
    const float C1 = 0.97f;
    const float C2 = (float)(1.0 - 0.97);   // match python double->f32
    const int colb = bn * 64 + wn * 32 + (l & 15);
    const int rowb = bm * 128 + wm * 64 + ((l >> 4) << 2);
    #pragma unroll
    for (int fi = 0; fi < 4; ++fi) {
        #pragma unroll
        for (int fj = 0; fj < 2; ++fj) {
            const int j = colb + fj * 16;
            const float bj = bias[j];
            #pragma unroll
            for (int v = 0; v < 4; ++v) {
                const int i = rowb + fi * 16 + v;
                const float val = acc[fi][fj][v] + bj;
                if constexpr (MODE == 1) {
                    const float a = fmaxf(val, 0.f);
                    aout[(size_t)i * N + j] = (_Float16)a;
                } else if constexpr (MODE == 3) {
                    outp[(size_t)i * N + j] = val;
                } else {
                    float hv;
                    if constexpr (MODE == 2) {
                        const float rres = (j >= 25) ? hold[(size_t)i * N + j - 25] : 0.f;
                        hv = C1 * rres + C2 * val;
                    } else {
                        hv = val;
                    }
                    hnew[(size_t)i * N + j] = hv;
                    if (rshift == 0) {
                        rnext[(size_t)i * N + j] = (_Float16)hv;
                    } else {
                        if (j + 25 < N) rnext[(size_t)i * N + j + 25] = (_Float16)hv;
                        if (j < 25)     rnext[(size_t)i * N + j]      = (_Float16)0.f;
                    }
                }
            }
        }
    }
}

__global__ void cvt_kernel(const float* __restrict__ in, _Float16* __restrict__ out, int n8)
{
    const int idx = blockIdx.x * 256 + threadIdx.x;
    if (idx < n8) {
        const floatx4 f0 = ((const floatx4*)in)[idx * 2];
        const floatx4 f1 = ((const floatx4*)in)[idx * 2 + 1];
        half8 h;
        #pragma unroll
        for (int i = 0; i < 4; ++i) {
            h[i]     = (_Float16)f0[i];
            h[4 + i] = (_Float16)f1[i];
        }
        ((half8*)out)[idx] = h;
    }
}

extern "C" void kernel_launch(void* const* d_in, const int* in_sizes, int n_in,
                              void* d_out, int out_size, void* d_ws, size_t ws_size,
                              hipStream_t stream)
{
    (void)in_sizes; (void)n_in; (void)out_size; (void)ws_size;
    const float* x     = (const float*)d_in[0];
    const float* fc1_w = (const float*)d_in[1];
    const float* fc1_b = (const float*)d_in[2];
    const float* W1    = (const float*)d_in[3];
    const float* b1    = (const float*)d_in[4];
    const float* W2    = (const float*)d_in[5];
    const float* b2    = (const float*)d_in[6];
    const float* fc2_w = (const float*)d_in[7];
    const float* fc2_b = (const float*)d_in[8];
    float* out = (float*)d_out;

    char* ws = (char*)d_ws;
    _Float16* xh = (_Float16*)(ws);                    // 4 MiB  [4096][512]
    _Float16* rb = (_Float16*)(ws + (4ull  << 20));    // 8 MiB  [4096][1024]
    _Float16* ab = (_Float16*)(ws + (12ull << 20));    // 8 MiB  [4096][1024]
    float*    h0 = (float*)   (ws + (20ull << 20));    // 16 MiB [4096][1024]
    float*    h1 = (float*)   (ws + (36ull << 20));    // 16 MiB [4096][1024]

    // x -> fp16
    cvt_kernel<<<dim3((MROWS * 512 / 8 + 255) / 256), dim3(256), 0, stream>>>(x, xh, MROWS * 512 / 8);

    // fc1: h0 = x @ fc1_w^T + fc1_b ; rb = fp16(shift(h0))
    gemm_k<0><<<dim3(HID / 64, MROWS / 128), dim3(256), 0, stream>>>(
        xh, fc1_w, fc1_b, nullptr, h0, rb, nullptr, nullptr, HID, 512, 25);

    for (int d = 0; d < DEPTH; ++d) {
        const float* w1 = W1 + (size_t)d * HID * HID;
        const float* w2 = W2 + (size_t)d * HID * HID;
        float* hold = (d & 1) ? h1 : h0;
        float* hnw  = (d & 1) ? h0 : h1;
        // a = fp16(relu(rb @ w1^T + b1))
        gemm_k<1><<<dim3(HID / 64, MROWS / 128), dim3(256), 0, stream>>>(
            rb, w1, b1 + (size_t)d * HID, nullptr, nullptr, nullptr, ab, nullptr, HID, HID, 0);
        // hnew = 0.97*shift(hold) + 0.03*(a @ w2^T + b2) ; rb = fp16(shift(hnew)) (unshifted on last)
        gemm_k<2><<<dim3(HID / 64, MROWS / 128), dim3(256), 0, stream>>>(
            ab, w2, b2 + (size_t)d * HID, hold, hnw, rb, nullptr, nullptr, HID, HID, (d == DEPTH - 1) ? 0 : 25);
    }

    // out = h100 @ fc2_w^T + fc2_b
    gemm_k<3><<<dim3(512 / 64, MROWS / 128), dim3(256), 0, stream>>>(
        rb, fc2_w, fc2_b, nullptr, nullptr, nullptr, nullptr, out, 512, HID, 0);
}

// Round 2
// 6397.998 us; speedup vs baseline: 1.1484x; 1.1484x over previous
//
#include <hip/hip_runtime.h>
#include <cstdint>
#include <cstddef>

#define DEPTH 100
#define HID 1024
#define MROWS 4096

typedef _Float16 half8 __attribute__((ext_vector_type(8)));
typedef float floatx4 __attribute__((ext_vector_type(4)));

__device__ __forceinline__ void gload_lds16(const void* g, void* l) {
    __builtin_amdgcn_global_load_lds((const __attribute__((address_space(1))) void*)g,
                                     (__attribute__((address_space(3))) void*)l,
                                     16, 0, 0);
}

// ============================================================================
// FAST PATH: C[M,N] = A[M,K](fp16) * B[N,K](fp16)^T, 128x128 tile, 4 waves,
// wave tile 64x64 (acc 4x4), 3-deep LDS pipeline, raw barriers + counted vmcnt.
// MODE 0: fc1  -> hnew(fp32) + rnext(fp16, shifted)
// MODE 1: blk1 -> aout = fp16(relu(acc+bias))
// MODE 2: blk2 -> hnew = 0.97*shift(hold) + 0.03*(acc+bias); rnext = fp16(shift(hnew))
// MODE 3: fc2  -> outp(fp32)
// ============================================================================
template<int MODE>
__global__ __launch_bounds__(256, 1)
void gemm_f(const _Float16* __restrict__ A, const _Float16* __restrict__ B,
            const float* __restrict__ bias, const float* __restrict__ hold,
            float* __restrict__ hnew, _Float16* __restrict__ rnext,
            _Float16* __restrict__ aout, float* __restrict__ outp,
            int N, int K, int rshift, int nbnl)
{
    __shared__ _Float16 As[3][128 * 64];
    __shared__ _Float16 Bs[3][128 * 64];

    const int tid = threadIdx.x;
    const int l   = tid & 63;
    const int w   = tid >> 6;        // wave 0..3
    const int wm  = w >> 1;          // 0..1 along M
    const int wn  = w & 1;           // 0..1 along N

    // XCD-aware bijective swizzle (gridDim.x % 8 == 0 always here)
    const int cpx = gridDim.x >> 3;
    const int b0  = blockIdx.x;
    const int bid = (b0 & 7) * cpx + (b0 >> 3);
    const int bn  = bid & ((1 << nbnl) - 1);
    const int bm  = bid >> nbnl;

    floatx4 acc[4][4];
    const floatx4 zero = {0.f, 0.f, 0.f, 0.f};
    #pragma unroll
    for (int i = 0; i < 4; ++i)
        #pragma unroll
        for (int j = 0; j < 4; ++j) acc[i][j] = zero;

    // staging geometry: 16 chunks of 1KB per tile (chunk = 8 rows x 64 fp16),
    // LDS linear, source column pre-swizzled (XOR bits 4-6 of byte offset)
    const int lr = l >> 3;           // row within chunk 0..7
    const int lj = l & 7;            // 16B column slot 0..7
    const int sw = (l & 7) << 4;     // fragment-read swizzle

    auto stage = [&](int buf, int kt) {
        #pragma unroll
        for (int q = 0; q < 4; ++q) {
            const int c   = w + 4 * q;
            const int row = c * 8 + lr;
            const int jch = lj ^ (row & 7);
            gload_lds16((const void*)(A + (size_t)(bm * 128 + row) * K + kt * 64 + jch * 8),
                        (void*)((char*)As[buf] + c * 1024));
        }
        #pragma unroll
        for (int q = 0; q < 4; ++q) {
            const int c   = w + 4 * q;
            const int row = c * 8 + lr;
            const int jch = lj ^ (row & 7);
            gload_lds16((const void*)(B + (size_t)(bn * 128 + row) * K + kt * 64 + jch * 8),
                        (void*)((char*)Bs[buf] + c * 1024));
        }
    };

    auto compute = [&](int buf) {
        #pragma unroll
        for (int kk = 0; kk < 2; ++kk) {
            half8 af[4], bf[4];
            #pragma unroll
            for (int fi = 0; fi < 4; ++fi) {
                const int off = ((wm * 64 + fi * 16 + (l & 15)) * 128 + kk * 64 + ((l >> 4) << 4)) ^ sw;
                af[fi] = *(const half8*)((const char*)As[buf] + off);
            }
            #pragma unroll
            for (int fj = 0; fj < 4; ++fj) {
                const int off = ((wn * 64 + fj * 16 + (l & 15)) * 128 + kk * 64 + ((l >> 4) << 4)) ^ sw;
                bf[fj] = *(const half8*)((const char*)Bs[buf] + off);
            }
            #pragma unroll
            for (int fi = 0; fi < 4; ++fi)
                #pragma unroll
                for (int fj = 0; fj < 4; ++fj)
                    acc[fi][fj] = __builtin_amdgcn_mfma_f32_16x16x32_f16(af[fi], bf[fj], acc[fi][fj], 0, 0, 0);
        }
    };

    const int nkt = K >> 6;
    stage(0, 0);
    if (nkt > 1) stage(1, 1);
    int cur = 0;
    for (int kt = 0; kt < nkt; ++kt) {
        if (kt + 2 < nkt) {
            int n2 = cur + 2; if (n2 >= 3) n2 -= 3;
            stage(n2, kt + 2);
        }
        const int rem   = nkt - 1 - kt;
        const int ahead = rem < 2 ? rem : 2;   // stages still in flight after issue
        if (ahead == 2)      asm volatile("s_waitcnt vmcnt(16)" ::: "memory");
        else if (ahead == 1) asm volatile("s_waitcnt vmcnt(8)"  ::: "memory");
        else                 asm volatile("s_waitcnt vmcnt(0)"  ::: "memory");
        __builtin_amdgcn_s_barrier();
        __builtin_amdgcn_sched_barrier(0);
        compute(cur);
        __builtin_amdgcn_s_barrier();
        cur = (cur + 1 == 3) ? 0 : cur + 1;
    }

    // ---- epilogue ----
    const float C1 = 0.97f;
    const float C2 = (float)(1.0 - 0.97);
    const int colb = bn * 128 + wn * 64 + (l & 15);
    const int rowb = bm * 128 + wm * 64 + ((l >> 4) << 2);
    #pragma unroll
    for (int fi = 0; fi < 4; ++fi) {
        #pragma unroll
        for (int fj = 0; fj < 4; ++fj) {
            const int j = colb + fj * 16;
            const float bj = bias[j];
            #pragma unroll
            for (int v = 0; v < 4; ++v) {
                const int i = rowb + fi * 16 + v;
                const float val = acc[fi][fj][v] + bj;
                if constexpr (MODE == 1) {
                    aout[(size_t)i * N + j] = (_Float16)fmaxf(val, 0.f);
                } else if constexpr (MODE == 3) {
                    outp[(size_t)i * N + j] = val;
                } else {
                    float hv;
                    if constexpr (MODE == 2) {
                        const float rres = (j >= 25) ? hold[(size_t)i * N + j - 25] : 0.f;
                        hv = C1 * rres + C2 * val;
                    } else {
                        hv = val;
                    }
                    hnew[(size_t)i * N + j] = hv;
                    if (rshift == 0) {
                        rnext[(size_t)i * N + j] = (_Float16)hv;
                    } else {
                        if (j + 25 < N) rnext[(size_t)i * N + j + 25] = (_Float16)hv;
                        if (j < 25)     rnext[(size_t)i * N + j]      = (_Float16)0.f;
                    }
                }
            }
        }
    }
}

// ============================================================================
// FALLBACK (ws too small): round-1 kernel, B read as fp32 directly. Verified.
// ============================================================================
template<int MODE>
__global__ __launch_bounds__(256, 2)
void gemm_k(const _Float16* __restrict__ A, const float* __restrict__ B,
            const float* __restrict__ bias, const float* __restrict__ hold,
            float* __restrict__ hnew, _Float16* __restrict__ rnext,
            _Float16* __restrict__ aout, float* __restrict__ outp,
            int N, int K, int rshift)
{
    __shared__ _Float16 As[128 * 64];
    __shared__ _Float16 Bs[64 * 64];

    const int tid = threadIdx.x;
    const int l   = tid & 63;
    const int w   = tid >> 6;
    const int wm  = w >> 1;
    const int wn  = w & 1;
    const int bn  = blockIdx.x;
    const int bm  = blockIdx.y;

    floatx4 acc[4][2];
    const floatx4 zero = {0.f, 0.f, 0.f, 0.f};
    #pragma unroll
    for (int i = 0; i < 4; ++i)
        #pragma unroll
        for (int j = 0; j < 2; ++j) acc[i][j] = zero;

    const int lr = l >> 3;
    const int lj = l & 7;
    const int br = tid >> 2;
    const int bq = tid & 3;
    const int sw = (l & 7) << 4;

    const int nkt = K >> 6;
    for (int kt = 0; kt < nkt; ++kt) {
        __syncthreads();
        #pragma unroll
        for (int q = 0; q < 4; ++q) {
            const int c   = w + 4 * q;
            const int row = c * 8 + lr;
            const int jch = lj ^ (row & 7);
            const _Float16* src = A + (size_t)(bm * 128 + row) * K + kt * 64 + jch * 8;
            gload_lds16((const void*)src, (void*)((char*)As + c * 1024));
        }
        {
            const float* bsrc = B + (size_t)(bn * 64 + br) * K + kt * 64 + bq * 16;
            const floatx4 f0 = ((const floatx4*)bsrc)[0];
            const floatx4 f1 = ((const floatx4*)bsrc)[1];
            const floatx4 f2 = ((const floatx4*)bsrc)[2];
            const floatx4 f3 = ((const floatx4*)bsrc)[3];
            half8 h0, h1;
            #pragma unroll
            for (int i = 0; i < 4; ++i) {
                h0[i]     = (_Float16)f0[i];
                h0[4 + i] = (_Float16)f1[i];
                h1[i]     = (_Float16)f2[i];
                h1[4 + i] = (_Float16)f3[i];
            }
            const int ob = br * 128 + bq * 32;
            const int s  = (br & 7) << 4;
            *(half8*)((char*)Bs + ((ob)      ^ s)) = h0;
            *(half8*)((char*)Bs + ((ob + 16) ^ s)) = h1;
        }
        __syncthreads();
        #pragma unroll
        for (int kk = 0; kk < 2; ++kk) {
            half8 af[4], bf[2];
            #pragma unroll
            for (int fi = 0; fi < 4; ++fi) {
                const int off = ((wm * 64 + fi * 16 + (l & 15)) * 128 + kk * 64 + ((l >> 4) << 4)) ^ sw;
                af[fi] = *(const half8*)((const char*)As + off);
            }
            #pragma unroll
            for (int fj = 0; fj < 2; ++fj) {
                const int off = ((wn * 32 + fj * 16 + (l & 15)) * 128 + kk * 64 + ((l >> 4) << 4)) ^ sw;
                bf[fj] = *(const half8*)((const char*)Bs + off);
            }
            #pragma unroll
            for (int fi = 0; fi < 4; ++fi)
                #pragma unroll
                for (int fj = 0; fj < 2; ++fj)
                    acc[fi][fj] = __builtin_amdgcn_mfma_f32_16x16x32_f16(af[fi], bf[fj], acc[fi][fj], 0, 0, 0);
        }
    }

    const float C1 = 0.97f;
    const float C2 = (float)(1.0 - 0.97);
    const int colb = bn * 64 + wn * 32 + (l & 15);
    const int rowb = bm * 128 + wm * 64 + ((l >> 4) << 2);
    #pragma unroll
    for (int fi = 0; fi < 4; ++fi) {
        #pragma unroll
        for (int fj = 0; fj < 2; ++fj) {
            const int j = colb + fj * 16;
            const float bj = bias[j];
            #pragma unroll
            for (int v = 0; v < 4; ++v) {
                const int i = rowb + fi * 16 + v;
                const float val = acc[fi][fj][v] + bj;
                if constexpr (MODE == 1) {
                    aout[(size_t)i * N + j] = (_Float16)fmaxf(val, 0.f);
                } else if constexpr (MODE == 3) {
                    outp[(size_t)i * N + j] = val;
                } else {
                    float hv;
                    if constexpr (MODE == 2) {
                        const float rres = (j >= 25) ? hold[(size_t)i * N + j - 25] : 0.f;
                        hv = C1 * rres + C2 * val;
                    } else {
                        hv = val;
                    }
                    hnew[(size_t)i * N + j] = hv;
                    if (rshift == 0) {
                        rnext[(size_t)i * N + j] = (_Float16)hv;
                    } else {
                        if (j + 25 < N) rnext[(size_t)i * N + j + 25] = (_Float16)hv;
                        if (j < 25)     rnext[(size_t)i * N + j]      = (_Float16)0.f;
                    }
                }
            }
        }
    }
}

__global__ void cvt_kernel(const float* __restrict__ in, _Float16* __restrict__ out, long n8)
{
    const long stride = (long)gridDim.x * 256;
    for (long idx = (long)blockIdx.x * 256 + threadIdx.x; idx < n8; idx += stride) {
        const floatx4 f0 = ((const floatx4*)in)[idx * 2];
        const floatx4 f1 = ((const floatx4*)in)[idx * 2 + 1];
        half8 h;
        #pragma unroll
        for (int i = 0; i < 4; ++i) {
            h[i]     = (_Float16)f0[i];
            h[4 + i] = (_Float16)f1[i];
        }
        ((half8*)out)[idx] = h;
    }
}

static inline void launch_cvt(const float* in, _Float16* out, long n, hipStream_t s)
{
    const long n8 = n / 8;
    int blocks = (int)((n8 + 255) / 256);
    if (blocks > 2048) blocks = 2048;
    cvt_kernel<<<dim3(blocks), dim3(256), 0, s>>>(in, out, n8);
}

extern "C" void kernel_launch(void* const* d_in, const int* in_sizes, int n_in,
                              void* d_out, int out_size, void* d_ws, size_t ws_size,
                              hipStream_t stream)
{
    (void)in_sizes; (void)n_in; (void)out_size;
    const float* x     = (const float*)d_in[0];
    const float* fc1_w = (const float*)d_in[1];
    const float* fc1_b = (const float*)d_in[2];
    const float* W1    = (const float*)d_in[3];
    const float* b1    = (const float*)d_in[4];
    const float* W2    = (const float*)d_in[5];
    const float* b2    = (const float*)d_in[6];
    const float* fc2_w = (const float*)d_in[7];
    const float* fc2_b = (const float*)d_in[8];
    float* out = (float*)d_out;

    char* ws = (char*)d_ws;
    _Float16* xh = (_Float16*)(ws);                    // 4 MiB  [4096][512]
    _Float16* rb = (_Float16*)(ws + (4ull  << 20));    // 8 MiB  [4096][1024]
    _Float16* ab = (_Float16*)(ws + (12ull << 20));    // 8 MiB  [4096][1024]
    float*    h0 = (float*)   (ws + (20ull << 20));    // 16 MiB
    float*    h1 = (float*)   (ws + (36ull << 20));    // 16 MiB

    const bool fast = ws_size >= (456ull << 20);

    launch_cvt(x, xh, (long)MROWS * 512, stream);

    if (fast) {
        _Float16* fc1h = (_Float16*)(ws + (52ull  << 20));  // 1 MiB [1024][512]
        _Float16* fc2h = (_Float16*)(ws + (53ull  << 20));  // 1 MiB [512][1024]
        _Float16* W1h  = (_Float16*)(ws + (54ull  << 20));  // 200 MiB
        _Float16* W2h  = (_Float16*)(ws + (254ull << 20));  // 200 MiB

        launch_cvt(fc1_w, fc1h, (long)HID * 512, stream);
        launch_cvt(W1,    W1h,  (long)DEPTH * HID * HID, stream);
        launch_cvt(W2,    W2h,  (long)DEPTH * HID * HID, stream);
        launch_cvt(fc2_w, fc2h, (long)512 * HID, stream);

        // fc1: h0 = x @ fc1_w^T + fc1_b ; rb = fp16(shift(h0))   grid 32*8=256
        gemm_f<0><<<dim3(32 * 8), dim3(256), 0, stream>>>(
            xh, fc1h, fc1_b, nullptr, h0, rb, nullptr, nullptr, HID, 512, 25, 3);

        for (int d = 0; d < DEPTH; ++d) {
            const _Float16* w1 = W1h + (size_t)d * HID * HID;
            const _Float16* w2 = W2h + (size_t)d * HID * HID;
            float* hold = (d & 1) ? h1 : h0;
            float* hnw  = (d & 1) ? h0 : h1;
            gemm_f<1><<<dim3(32 * 8), dim3(256), 0, stream>>>(
                rb, w1, b1 + (size_t)d * HID, nullptr, nullptr, nullptr, ab, nullptr,
                HID, HID, 0, 3);
            gemm_f<2><<<dim3(32 * 8), dim3(256), 0, stream>>>(
                ab, w2, b2 + (size_t)d * HID, hold, hnw, rb, nullptr, nullptr,
                HID, HID, (d == DEPTH - 1) ? 0 : 25, 3);
        }

        // fc2: out = h100 @ fc2_w^T + fc2_b   grid 32*4=128
        gemm_f<3><<<dim3(32 * 4), dim3(256), 0, stream>>>(
            rb, fc2h, fc2_b, nullptr, nullptr, nullptr, nullptr, out, 512, HID, 0, 2);
    } else {
        gemm_k<0><<<dim3(HID / 64, MROWS / 128), dim3(256), 0, stream>>>(
            xh, fc1_w, fc1_b, nullptr, h0, rb, nullptr, nullptr, HID, 512, 25);
        for (int d = 0; d < DEPTH; ++d) {
            const float* w1 = W1 + (size_t)d * HID * HID;
            const float* w2 = W2 + (size_t)d * HID * HID;
            float* hold = (d & 1) ? h1 : h0;
            float* hnw  = (d & 1) ? h0 : h1;
            gemm_k<1><<<dim3(HID / 64, MROWS / 128), dim3(256), 0, stream>>>(
                rb, w1, b1 + (size_t)d * HID, nullptr, nullptr, nullptr, ab, nullptr, HID, HID, 0);
            gemm_k<2><<<dim3(HID / 64, MROWS / 128), dim3(256), 0, stream>>>(
                ab, w2, b2 + (size_t)d * HID, hold, hnw, rb, nullptr, nullptr, HID, HID,
                (d == DEPTH - 1) ? 0 : 25);
        }
        gemm_k<3><<<dim3(512 / 64, MROWS / 128), dim3(256), 0, stream>>>(
            rb, fc2_w, fc2_b, nullptr, nullptr, nullptr, nullptr, out, 512, HID, 0);
    }
}

// Round 3
// 5687.807 us; speedup vs baseline: 1.2918x; 1.1249x over previous
//
#include <hip/hip_runtime.h>
#include <cstdint>
#include <cstddef>

#define DEPTH 100
#define HID 1024
#define MROWS 4096

typedef _Float16 half8 __attribute__((ext_vector_type(8)));
typedef float floatx4 __attribute__((ext_vector_type(4)));

__device__ __forceinline__ void gload_lds16(const void* g, void* l) {
    __builtin_amdgcn_global_load_lds((const __attribute__((address_space(1))) void*)g,
                                     (__attribute__((address_space(3))) void*)l,
                                     16, 0, 0);
}

// ============================================================================
// C[M,N] = A[M,K](fp16) * B[N,K](fp16)^T, 128x128 tile, 8 waves (512 thr),
// wave tile 64x32 (acc 4x2), 3-deep LDS pipeline, counted vmcnt, setprio.
// Grid is only 256 blocks at this problem shape -> 1 block/CU; occupancy must
// come from 8 waves = 2 waves/SIMD so MFMA and LDS/stage phases co-schedule.
// MODE 0: fc1  -> hnew(fp32) + rnext(fp16, shifted)
// MODE 1: blk1 -> aout = fp16(relu(acc+bias))
// MODE 2: blk2 -> hnew = 0.97*shift(hold) + 0.03*(acc+bias); rnext = fp16(shift(hnew))
// MODE 3: fc2  -> outp(fp32)
// ============================================================================
template<int MODE>
__global__ __launch_bounds__(512, 1)
void gemm_f(const _Float16* __restrict__ A, const _Float16* __restrict__ B,
            const float* __restrict__ bias, const float* __restrict__ hold,
            float* __restrict__ hnew, _Float16* __restrict__ rnext,
            _Float16* __restrict__ aout, float* __restrict__ outp,
            int N, int K, int rshift, int nbnl)
{
    __shared__ _Float16 As[3][128 * 64];
    __shared__ _Float16 Bs[3][128 * 64];

    const int tid = threadIdx.x;
    const int l   = tid & 63;
    const int w   = tid >> 6;        // wave 0..7
    const int wm  = w >> 2;          // 0..1 along M (64 rows each)
    const int wn  = w & 3;           // 0..3 along N (32 cols each)

    // XCD-aware bijective swizzle (gridDim.x % 8 == 0 always here)
    const int cpx = gridDim.x >> 3;
    const int b0  = blockIdx.x;
    const int bid = (b0 & 7) * cpx + (b0 >> 3);
    const int bn  = bid & ((1 << nbnl) - 1);
    const int bm  = bid >> nbnl;

    floatx4 acc[4][2];
    const floatx4 zero = {0.f, 0.f, 0.f, 0.f};
    #pragma unroll
    for (int i = 0; i < 4; ++i)
        #pragma unroll
        for (int j = 0; j < 2; ++j) acc[i][j] = zero;

    // staging geometry: tile = 16 chunks of 1KB (chunk = 8 rows x 64 fp16),
    // LDS linear, source column pre-swizzled (XOR bits 4-6 of byte offset).
    // 8 waves -> 2 A-chunks + 2 B-chunks per wave = 4 gload_lds per stage.
    const int lr = l >> 3;           // row within chunk 0..7
    const int lj = l & 7;            // 16B column slot 0..7
    const int sw = (l & 7) << 4;     // fragment-read swizzle

    auto stage = [&](int buf, int kt) {
        #pragma unroll
        for (int q = 0; q < 2; ++q) {
            const int c   = w * 2 + q;
            const int row = c * 8 + lr;
            const int jch = lj ^ (row & 7);
            gload_lds16((const void*)(A + (size_t)(bm * 128 + row) * K + kt * 64 + jch * 8),
                        (void*)((char*)As[buf] + c * 1024));
        }
        #pragma unroll
        for (int q = 0; q < 2; ++q) {
            const int c   = w * 2 + q;
            const int row = c * 8 + lr;
            const int jch = lj ^ (row & 7);
            gload_lds16((const void*)(B + (size_t)(bn * 128 + row) * K + kt * 64 + jch * 8),
                        (void*)((char*)Bs[buf] + c * 1024));
        }
    };

    auto compute = [&](int buf) {
        #pragma unroll
        for (int kk = 0; kk < 2; ++kk) {
            half8 af[4], bf[2];
            #pragma unroll
            for (int fi = 0; fi < 4; ++fi) {
                const int off = ((wm * 64 + fi * 16 + (l & 15)) * 128 + kk * 64 + ((l >> 4) << 4)) ^ sw;
                af[fi] = *(const half8*)((const char*)As[buf] + off);
            }
            #pragma unroll
            for (int fj = 0; fj < 2; ++fj) {
                const int off = ((wn * 32 + fj * 16 + (l & 15)) * 128 + kk * 64 + ((l >> 4) << 4)) ^ sw;
                bf[fj] = *(const half8*)((const char*)Bs[buf] + off);
            }
            __builtin_amdgcn_s_setprio(1);
            #pragma unroll
            for (int fi = 0; fi < 4; ++fi)
                #pragma unroll
                for (int fj = 0; fj < 2; ++fj)
                    acc[fi][fj] = __builtin_amdgcn_mfma_f32_16x16x32_f16(af[fi], bf[fj], acc[fi][fj], 0, 0, 0);
            __builtin_amdgcn_s_setprio(0);
        }
    };

    const int nkt = K >> 6;
    stage(0, 0);
    if (nkt > 1) stage(1, 1);
    int cur = 0;
    for (int kt = 0; kt < nkt; ++kt) {
        if (kt + 2 < nkt) {
            int n2 = cur + 2; if (n2 >= 3) n2 -= 3;
            stage(n2, kt + 2);
        }
        const int rem   = nkt - 1 - kt;
        const int ahead = rem < 2 ? rem : 2;   // stages still in flight after issue
        if (ahead == 2)      asm volatile("s_waitcnt vmcnt(8)" ::: "memory");
        else if (ahead == 1) asm volatile("s_waitcnt vmcnt(4)" ::: "memory");
        else                 asm volatile("s_waitcnt vmcnt(0)" ::: "memory");
        __builtin_amdgcn_s_barrier();
        __builtin_amdgcn_sched_barrier(0);
        compute(cur);
        __builtin_amdgcn_s_barrier();
        cur = (cur + 1 == 3) ? 0 : cur + 1;
    }

    // ---- epilogue ----
    const float C1 = 0.97f;
    const float C2 = (float)(1.0 - 0.97);
    const int colb = bn * 128 + wn * 32 + (l & 15);
    const int rowb = bm * 128 + wm * 64 + ((l >> 4) << 2);
    #pragma unroll
    for (int fi = 0; fi < 4; ++fi) {
        #pragma unroll
        for (int fj = 0; fj < 2; ++fj) {
            const int j = colb + fj * 16;
            const float bj = bias[j];
            #pragma unroll
            for (int v = 0; v < 4; ++v) {
                const int i = rowb + fi * 16 + v;
                const float val = acc[fi][fj][v] + bj;
                if constexpr (MODE == 1) {
                    aout[(size_t)i * N + j] = (_Float16)fmaxf(val, 0.f);
                } else if constexpr (MODE == 3) {
                    outp[(size_t)i * N + j] = val;
                } else {
                    float hv;
                    if constexpr (MODE == 2) {
                        const float rres = (j >= 25) ? hold[(size_t)i * N + j - 25] : 0.f;
                        hv = C1 * rres + C2 * val;
                    } else {
                        hv = val;
                    }
                    hnew[(size_t)i * N + j] = hv;
                    if (rshift == 0) {
                        rnext[(size_t)i * N + j] = (_Float16)hv;
                    } else {
                        if (j + 25 < N) rnext[(size_t)i * N + j + 25] = (_Float16)hv;
                        if (j < 25)     rnext[(size_t)i * N + j]      = (_Float16)0.f;
                    }
                }
            }
        }
    }
}

__global__ void cvt_kernel(const float* __restrict__ in, _Float16* __restrict__ out, long n8)
{
    const long stride = (long)gridDim.x * 256;
    for (long idx = (long)blockIdx.x * 256 + threadIdx.x; idx < n8; idx += stride) {
        const floatx4 f0 = ((const floatx4*)in)[idx * 2];
        const floatx4 f1 = ((const floatx4*)in)[idx * 2 + 1];
        half8 h;
        #pragma unroll
        for (int i = 0; i < 4; ++i) {
            h[i]     = (_Float16)f0[i];
            h[4 + i] = (_Float16)f1[i];
        }
        ((half8*)out)[idx] = h;
    }
}

static inline void launch_cvt(const float* in, _Float16* out, long n, hipStream_t s)
{
    const long n8 = n / 8;
    int blocks = (int)((n8 + 255) / 256);
    if (blocks > 2048) blocks = 2048;
    cvt_kernel<<<dim3(blocks), dim3(256), 0, s>>>(in, out, n8);
}

extern "C" void kernel_launch(void* const* d_in, const int* in_sizes, int n_in,
                              void* d_out, int out_size, void* d_ws, size_t ws_size,
                              hipStream_t stream)
{
    (void)in_sizes; (void)n_in; (void)out_size; (void)ws_size;
    const float* x     = (const float*)d_in[0];
    const float* fc1_w = (const float*)d_in[1];
    const float* fc1_b = (const float*)d_in[2];
    const float* W1    = (const float*)d_in[3];
    const float* b1    = (const float*)d_in[4];
    const float* W2    = (const float*)d_in[5];
    const float* b2    = (const float*)d_in[6];
    const float* fc2_w = (const float*)d_in[7];
    const float* fc2_b = (const float*)d_in[8];
    float* out = (float*)d_out;

    char* ws = (char*)d_ws;
    _Float16* xh = (_Float16*)(ws);                    // 4 MiB  [4096][512]
    _Float16* rb = (_Float16*)(ws + (4ull  << 20));    // 8 MiB  [4096][1024]
    _Float16* ab = (_Float16*)(ws + (12ull << 20));    // 8 MiB  [4096][1024]
    float*    h0 = (float*)   (ws + (20ull << 20));    // 16 MiB
    float*    h1 = (float*)   (ws + (36ull << 20));    // 16 MiB
    _Float16* fc1h = (_Float16*)(ws + (52ull  << 20)); // 1 MiB  [1024][512]
    _Float16* fc2h = (_Float16*)(ws + (53ull  << 20)); // 1 MiB  [512][1024]
    _Float16* W1h  = (_Float16*)(ws + (54ull  << 20)); // 200 MiB
    _Float16* W2h  = (_Float16*)(ws + (254ull << 20)); // 200 MiB

    launch_cvt(x, xh, (long)MROWS * 512, stream);
    launch_cvt(fc1_w, fc1h, (long)HID * 512, stream);
    launch_cvt(W1,    W1h,  (long)DEPTH * HID * HID, stream);
    launch_cvt(W2,    W2h,  (long)DEPTH * HID * HID, stream);
    launch_cvt(fc2_w, fc2h, (long)512 * HID, stream);

    // fc1: h0 = x @ fc1_w^T + fc1_b ; rb = fp16(shift(h0))   grid 32*8=256
    gemm_f<0><<<dim3(32 * 8), dim3(512), 0, stream>>>(
        xh, fc1h, fc1_b, nullptr, h0, rb, nullptr, nullptr, HID, 512, 25, 3);

    for (int d = 0; d < DEPTH; ++d) {
        const _Float16* w1 = W1h + (size_t)d * HID * HID;
        const _Float16* w2 = W2h + (size_t)d * HID * HID;
        float* hold = (d & 1) ? h1 : h0;
        float* hnw  = (d & 1) ? h0 : h1;
        gemm_f<1><<<dim3(32 * 8), dim3(512), 0, stream>>>(
            rb, w1, b1 + (size_t)d * HID, nullptr, nullptr, nullptr, ab, nullptr,
            HID, HID, 0, 3);
        gemm_f<2><<<dim3(32 * 8), dim3(512), 0, stream>>>(
            ab, w2, b2 + (size_t)d * HID, hold, hnw, rb, nullptr, nullptr,
            HID, HID, (d == DEPTH - 1) ? 0 : 25, 3);
    }

    // fc2: out = h100 @ fc2_w^T + fc2_b   grid 32*4=128
    gemm_f<3><<<dim3(32 * 4), dim3(512), 0, stream>>>(
        rb, fc2h, fc2_b, nullptr, nullptr, nullptr, nullptr, out, 512, HID, 0, 2);
}